// Round 14
// baseline (169.725 us; speedup 1.0000x reference)
//
#include <hip/hip_runtime.h>
#include <math.h>

// Problem constants (from reference)
#define BB 4
#define TT 2048
#define CC 48
#define DD 512
#define LL 16
#define NTR 15
#define NCAND 45
#define WINLEN 19   // int(T/L*0.15)
#define CSW 15
#define CCHALF 7

static __device__ __forceinline__ float wave_reduce_sum(float v) {
    for (int off = 32; off; off >>= 1) v += __shfl_down(v, off);
    return v;
}

// DPP max step
#define DPPMAX(x, ctrl) fmaxf((x), __int_as_float(__builtin_amdgcn_update_dpp( \
    __float_as_int(x), __float_as_int(x), (ctrl), 0xF, 0xF, false)))

// ---------------- Kernel 1: JS score + inline LSE (4 t's/block) ----------------
// Block stages 12 rows once; 12 LSEs computed 3-per-wave (parallel), block writes
// lse for its own 4 rows. 3x LSE redundancy across blocks, fully parallel.
__global__ __launch_bounds__(256) void k_score(const float* __restrict__ fr,
                                               float* __restrict__ lse,
                                               float* __restrict__ score) {
    int t_base = (blockIdx.x * 4) % TT;
    int b = (blockIdx.x * 4) / TT;
    __shared__ float sp[12][CC];
    __shared__ float slp[12][CC];
    __shared__ float lse_s[12];
    int tid = threadIdx.x;
    int wave = tid >> 6, lane = tid & 63;
    // stage raw logits (0 for OOB rows)
    for (int idx = tid; idx < 12 * CC; idx += 256) {
        int i = idx / CC, c = idx - (idx / CC) * CC;
        int r = t_base - 4 + i;
        sp[i][c] = (r >= 0 && r < TT) ? fr[((size_t)b * TT + r) * CC + c] : 0.f;
    }
    __syncthreads();
    // wave w computes LSE for staged rows 3w..3w+2 (all 4 waves in parallel)
    for (int q = 0; q < 3; ++q) {
        int i = wave * 3 + q;
        int r = t_base - 4 + i;
        bool valid = (r >= 0 && r < TT);
        float xv = (lane < CC && valid) ? sp[i][lane] : -INFINITY;
        float m = xv;
        for (int off = 32; off; off >>= 1) m = fmaxf(m, __shfl_down(m, off));
        m = __shfl(m, 0);
        float e = (lane < CC && valid) ? __expf(xv - m) : 0.f;
        float s = wave_reduce_sum(e);
        if (lane == 0) lse_s[i] = valid ? (m + __logf(s)) : 0.f;
    }
    __syncthreads();
    // each element owned by one thread: convert x -> p, logp in place
    for (int idx = tid; idx < 12 * CC; idx += 256) {
        int i = idx / CC, c = idx - (idx / CC) * CC;
        int r = t_base - 4 + i;
        float lv = 0.f, pv = 0.f;
        if (r >= 0 && r < TT) { lv = sp[i][c] - lse_s[i]; pv = __expf(lv); }
        slp[i][c] = lv;
        sp[i][c] = pv;
    }
    __syncthreads();
    int t = t_base + wave;
    if (lane == 0) lse[(size_t)b * TT + t] = lse_s[wave + 4];   // own-row LSE out
    float acc = 0.f;
    for (int idx = lane; idx < 4 * CC; idx += 64) {
        int i = idx / CC, c = idx - (idx / CC) * CC;
        acc += -2.f * sp[wave + i][c] * slp[wave + i][c];
    }
    for (int item = lane; item < 36 * CC; item += 64) {
        int pidx = item / CC, c = item - pidx * CC;
        int i = 0, rem = pidx;
        while (rem >= 8 - i) { rem -= 8 - i; ++i; }
        int j = i + 1 + rem;
        float wgt = ((i < 4) == (j < 4)) ? 1.f : -1.f;
        float pi = sp[wave + i][c], pj = sp[wave + j][c];
        float logm = __logf(0.5f * (pi + pj) + 1e-32f);
        acc -= wgt * (pi + pj) * logm;
    }
    acc = wave_reduce_sum(acc);
    if (lane == 0) {
        const float SC = -2.0f / (81.0f * 0.6931471805599453f);
        score[(size_t)b * TT + t] = (t == 0) ? -INFINITY : SC * acc;
    }
}

// ---------------- Kernel 2: greedy pick, single wave, register-resident ----------------
__global__ __launch_bounds__(64) void k_pick(const float* __restrict__ score,
                                             int* __restrict__ cand,
                                             float* __restrict__ backup) {
    int b = blockIdx.x;
    int lane = threadIdx.x;
    __shared__ float s[64 * 33];
    __shared__ int cl[NCAND];
    for (int t = lane; t < TT; t += 64) s[t + (t >> 5)] = score[(size_t)b * TT + t];
    __syncthreads();
    float v[32];
    #pragma unroll
    for (int k = 0; k < 32; ++k) v[k] = s[lane * 33 + k];   // stride-33: conflict-free
    int base = lane << 5;
    for (int it = 0; it < NCAND; ++it) {
        float best = -INFINITY; int bi = 0;
        #pragma unroll
        for (int k = 31; k >= 0; --k)
            if (v[k] >= best) { best = v[k]; bi = k; }
        float m = best;
        m = DPPMAX(m, 0x111); m = DPPMAX(m, 0x112);
        m = DPPMAX(m, 0x114); m = DPPMAX(m, 0x118);
        m = DPPMAX(m, 0x142); m = DPPMAX(m, 0x143);
        float gmax = __int_as_float(__builtin_amdgcn_readlane(__float_as_int(m), 63));
        unsigned long long ball = __ballot(best == gmax);
        int sl = (int)(__ffsll((long long)ball) - 1);
        int mp = __builtin_amdgcn_readlane(base + bi, sl);
        if (lane == 0) cl[it] = mp;
        int llo = mp - WINLEN - base;
        int lhi = mp + WINLEN - base;
        unsigned lowm = (llo <= 0) ? 0xffffffffu : ((llo >= 32) ? 0u : ~((1u << llo) - 1u));
        unsigned him  = (lhi >= 31) ? 0xffffffffu : ((lhi < 0) ? 0u : ((2u << lhi) - 1u));
        unsigned wm = lowm & him;
        #pragma unroll
        for (int k = 0; k < 32; ++k)
            if (wm & (1u << k)) v[k] = -INFINITY;
    }
    __syncthreads();
    if (lane < NCAND) {
        int my = cl[lane];
        int rank = 0;
        for (int i = 0; i < NCAND; ++i) rank += (cl[i] < my) ? 1 : 0;
        cand[b * 64 + rank] = my;
        backup[b * 64 + rank] = s[my + (my >> 5)];
    }
}

// ---------------- Kernel 3: cls cost, one block per (candidate, batch) ----------------
__global__ __launch_bounds__(256) void k_cls(const float* __restrict__ fr,
                                             const float* __restrict__ lse,
                                             const int* __restrict__ cand,
                                             const float* __restrict__ backup,
                                             const int* __restrict__ transcript,
                                             float* __restrict__ cost_g) {
    int ii = blockIdx.x, b = blockIdx.y;
    __shared__ float win[CSW][LL + 1];
    __shared__ int tr_s[LL];
    int tid = threadIdx.x;
    if (tid < LL) tr_s[tid] = transcript[b * LL + tid];
    __syncthreads();
    int cpos = cand[b * 64 + ii];
    if (tid < CSW * LL) {
        int k = tid >> 4, m2 = tid & 15;
        int r = cpos - CCHALF + k;
        float p = 0.f;
        if (r >= 0 && r < TT) {
            size_t ro = (size_t)b * TT + r;
            p = __expf(fr[ro * CC + tr_s[m2]] - lse[ro]);
        }
        win[k][m2] = p;
    }
    __syncthreads();
    if (tid < NTR) {
        int j = tid;
        float sum = 0.f;
        #pragma unroll
        for (int k = 0; k < CSW; ++k)
            sum += ((k < CCHALF) ? 1.f : -1.f) * (win[k][j] - win[k][j + 1]);
        cost_g[(b * NTR + j) * NCAND + ii] = -(sum / 30.f + backup[b * 64 + ii]);
    }
}

// ---------------- Kernel 4: DP + backtrack + rank + frCE + la-zero ----------------
__global__ __launch_bounds__(256) void k_dp(const float* __restrict__ fr,
                                            const float* __restrict__ lse,
                                            const int* __restrict__ cand,
                                            const float* __restrict__ cost_g,
                                            const int* __restrict__ transcript,
                                            int* __restrict__ labels_out,
                                            int* __restrict__ rowmap,
                                            float* __restrict__ fr_part,
                                            float* __restrict__ la) {
    int b = blockIdx.x;
    __shared__ float cost[NTR][NCAND];
    __shared__ int tr_s[LL];
    __shared__ int cand_s[NCAND];
    __shared__ signed char dir_mat[NCAND][32];
    __shared__ int bdy_s[NTR];
    __shared__ int rank_s[LL];
    __shared__ float redf[4];
    int tid = threadIdx.x;
    int wave = tid >> 6, lane = tid & 63;
    if (tid < LL) tr_s[tid] = transcript[b * LL + tid];
    if (tid < NCAND) cand_s[tid] = cand[b * 64 + tid];

    // zero la for this batch (consumed later by k_la atomics)
    {
        float4 z = {0.f, 0.f, 0.f, 0.f};
        float4* lz = (float4*)(la + (size_t)b * LL * DD);
        #pragma unroll
        for (int i = 0; i < LL * DD / 4 / 256; ++i) lz[i * 256 + tid] = z;
    }
    // load precomputed cost matrix (675 floats)
    for (int e = tid; e < NTR * NCAND; e += 256) {
        int j = e / NCAND, ii = e - j * NCAND;
        cost[j][ii] = cost_g[b * NTR * NCAND + e];
    }
    __syncthreads();

    // ---- DP (wave 0, state j = lane j, W=31) ----
    if (tid < 64) {
        float prev = INFINITY;
        if (tid == 0) prev = 0.f;
        if (tid == 1) prev = cost[0][0];
        if (tid < 31) dir_mat[0][tid] = (tid == 1) ? (signed char)1 : (signed char)0;
        for (int ii = 1; ii < NCAND; ++ii) {
            float dm1 = __shfl_up(prev, 1); if (tid < 1) dm1 = INFINITY;
            float dm2 = __shfl_up(prev, 2); if (tid < 2) dm2 = INFINITY;
            int trat = tid >> 1; if (trat > NTR - 1) trat = NTR - 1;
            float c_at = cost[trat][ii];
            float ev = fminf(prev, dm1);
            int ed = (prev < dm1) ? 0 : 1;
            float ov = c_at + fminf(dm1, dm2);
            int od = (dm1 < dm2) ? 1 : 2;
            float nv; int nd;
            if (tid >= 2) {
                if ((tid & 1) == 0) { nv = ev; nd = ed; }
                else { nv = ov; nd = od; }
            } else { nv = INFINITY; nd = 0; }
            if (tid == 0) { nv = (ii < NCAND - NTR) ? 0.f : INFINITY; nd = 0; }
            if (tid == 1) {
                nv = (ii <= NCAND - NTR) ? cost[0][ii] : INFINITY;
                nd = (ii <= NCAND - NTR) ? 1 : 0;
            }
            prev = nv;
            if (tid < 31) dir_mat[ii][tid] = (signed char)nd;
        }
        float v29 = __shfl(prev, 29);
        float v30 = __shfl(prev, 30);
        if (tid == 0) {
            int cur = (v30 < v29) ? 30 : 29;
            for (int ii = NCAND - 1; ii >= 0; --ii) {
                if (cur & 1) bdy_s[cur >> 1] = cand_s[ii];
                cur -= (int)dir_mat[ii][cur];
            }
        }
    }
    __syncthreads();

    // ---- parallel rank (transcript values distinct) ----
    if (tid < LL) {
        int myv = tr_s[tid];
        int r2 = 0;
        #pragma unroll
        for (int l2 = 0; l2 < LL; ++l2) r2 += (tr_s[l2] < myv) ? 1 : 0;
        rank_s[tid] = r2;
        labels_out[b * LL + r2] = myv;   // sorted scatter
    }
    __syncthreads();

    // ---- fr CE partial + rowmap (pse inline) ----
    float facc = 0.f;
    for (int t = tid; t < TT; t += 256) {
        int cnt = 0;
        #pragma unroll
        for (int j = 0; j < NTR; ++j) cnt += (t >= bdy_s[j]) ? 1 : 0;
        int pv = tr_s[cnt];
        rowmap[b * TT + t] = rank_s[cnt];
        size_t ro = (size_t)b * TT + t;
        facc += lse[ro] - fr[ro * CC + pv];
    }
    facc = wave_reduce_sum(facc);
    if (lane == 0) redf[wave] = facc;
    __syncthreads();
    if (tid == 0) fr_part[b] = redf[0] + redf[1] + redf[2] + redf[3];
}

// ---------------- Kernel 5: segment feature sums, tile-scatter (atomics) ----------------
__global__ __launch_bounds__(256) void k_la(const float* __restrict__ feat,
                                            const int* __restrict__ rowmap,
                                            float* __restrict__ la) {
    int b = blockIdx.y;
    int t0 = blockIdx.x * 32;
    int tid = threadIdx.x;
    const float* frf = feat + ((size_t)b * (CC + TT) + CC) * DD;
    __shared__ int rm[32];
    if (tid < 32) rm[tid] = rowmap[b * TT + t0 + tid];
    __syncthreads();
    float ax = 0.f, ay = 0.f;
    int cur = rm[0];
    for (int k = 0; k < 32; ++k) {
        int r = rm[k];
        if (r != cur) {   // block-uniform branch
            float* dst = la + ((size_t)b * LL + cur) * DD + tid * 2;
            atomicAdd(dst, ax);
            atomicAdd(dst + 1, ay);
            ax = 0.f; ay = 0.f; cur = r;
        }
        const float2* p = (const float2*)(frf + (size_t)(t0 + k) * DD);
        float2 v = p[tid];
        ax += v.x; ay += v.y;
    }
    float* dst = la + ((size_t)b * LL + cur) * DD + tid * 2;
    atomicAdd(dst, ax);
    atomicAdd(dst + 1, ay);
}

// ---------------- Kernel 6: glc per (b,l): la staged, 48 dots + inline norms + term ----------------
__global__ __launch_bounds__(256) void k_glcterm(const float* __restrict__ feat,
                                                 const float* __restrict__ la,
                                                 const int* __restrict__ labels,
                                                 float* __restrict__ terms) {
    int l = blockIdx.x, b = blockIdx.y;
    __shared__ float la_s[DD];
    __shared__ float sim_s[CC];
    __shared__ float redv[4];
    int tid = threadIdx.x;
    int wave = tid >> 6, lane = tid & 63;
    const float* lar = la + ((size_t)b * LL + l) * DD;
    float2 lv = ((const float2*)lar)[tid];
    ((float2*)la_s)[tid] = lv;
    float ss = lv.x * lv.x + lv.y * lv.y;
    ss = wave_reduce_sum(ss);
    if (lane == 0) redv[wave] = ss;
    __syncthreads();
    float nla = fmaxf(sqrtf(redv[0] + redv[1] + redv[2] + redv[3]), 1e-12f);
    float inv_nla = 10.0f / nla;      // 1/TEMP folded
    for (int c = wave; c < CC; c += 4) {
        const float4* tr = (const float4*)(feat + ((size_t)b * (CC + TT) + c) * DD);
        const float4* ls = (const float4*)la_s;
        float dot = 0.f, vv = 0.f;
        #pragma unroll
        for (int jj = 0; jj < 2; ++jj) {
            int j = lane + jj * 64;
            float4 a = ls[j]; float4 w = tr[j];
            dot += a.x * w.x + a.y * w.y + a.z * w.z + a.w * w.w;
            vv  += w.x * w.x + w.y * w.y + w.z * w.z + w.w * w.w;
        }
        dot = wave_reduce_sum(dot);
        vv  = wave_reduce_sum(vv);
        if (lane == 0)
            sim_s[c] = dot * inv_nla / fmaxf(sqrtf(vv), 1e-12f);
    }
    __syncthreads();
    if (tid < 64) {
        float sim = (lane < CC) ? sim_s[lane] : -INFINITY;
        float mx = sim;
        for (int off = 32; off; off >>= 1) mx = fmaxf(mx, __shfl_down(mx, off));
        mx = __shfl(mx, 0);
        float e = (lane < CC) ? expf(sim - mx) : 0.f;
        float se = wave_reduce_sum(e);
        se = __shfl(se, 0);
        int lab = labels[b * LL + l];
        float sim_lab = __shfl(sim, lab);
        if (lane == 0) terms[b * LL + l] = (mx + logf(se)) - sim_lab;
    }
}

// ---------------- Kernel 7: combine ----------------
__global__ __launch_bounds__(256) void k_combine(const float* __restrict__ tok_logit,
                                                 const float* __restrict__ vid,
                                                 const float* __restrict__ fr_part,
                                                 const float* __restrict__ terms,
                                                 float* __restrict__ out) {
    int tid = threadIdx.x;
    __shared__ float red[4];
    __shared__ float gterm;
    float acc = 0.f;
    if (tid < BB * CC) {
        float x = tok_logit[tid], y = vid[tid];
        float lsp = fminf(x, 0.f) - log1pf(expf(-fabsf(x)));
        float lsn = fminf(-x, 0.f) - log1pf(expf(-fabsf(x)));
        acc = -(y * lsp + (1.f - y) * lsn);
    }
    float w = wave_reduce_sum(acc);
    if ((tid & 63) == 0) red[tid >> 6] = w;
    if (tid < 64) {
        float g = terms[tid];
        g = wave_reduce_sum(g);
        if (tid == 0) gterm = g;
    }
    __syncthreads();
    if (tid == 0) {
        float s_tok = (red[0] + red[1] + red[2] + red[3]) / (float)(BB * CC);
        float sfr = fr_part[0] + fr_part[1] + fr_part[2] + fr_part[3];
        float s_fr = sfr / (float)(BB * TT);
        float glc = gterm / (float)(BB * LL);
        out[0] = s_tok + s_fr + 0.1f * glc;
    }
}

extern "C" void kernel_launch(void* const* d_in, const int* in_sizes, int n_in,
                              void* d_out, int out_size, void* d_ws, size_t ws_size,
                              hipStream_t stream) {
    (void)in_sizes; (void)n_in; (void)out_size; (void)ws_size;
    // input order: epoch, tok_logit, fr_logit, mask, transcript, vid_multi_hot, feat
    const float* tok_logit  = (const float*)d_in[1];
    const float* fr_logit   = (const float*)d_in[2];
    const int*   transcript = (const int*)d_in[4];
    const float* vid        = (const float*)d_in[5];
    const float* feat       = (const float*)d_in[6];

    char* ws = (char*)d_ws;
    float* lse     = (float*)(ws + 0);        // B*T (32768 B)
    float* score   = (float*)(ws + 32768);    // B*T (32768 B)
    float* la      = (float*)(ws + 65536);    // B*L*D (131072 B)
    float* terms   = (float*)(ws + 209664);   // B*L
    float* fr_part = (float*)(ws + 209920);   // 4
    int*   labels  = (int*)(ws + 210176);     // B*L
    int*   rowmap  = (int*)(ws + 210432);     // B*T (32768 B)
    int*   cand    = (int*)(ws + 243200);     // B*64
    float* backup  = (float*)(ws + 244224);   // B*64
    float* cost_g  = (float*)(ws + 245248);   // B*NTR*NCAND (10800 B)
    float* out     = (float*)d_out;

    k_score<<<BB * TT / 4, 256, 0, stream>>>(fr_logit, lse, score);
    k_pick<<<BB, 64, 0, stream>>>(score, cand, backup);
    k_cls<<<dim3(NCAND, BB), 256, 0, stream>>>(fr_logit, lse, cand, backup,
                                               transcript, cost_g);
    k_dp<<<BB, 256, 0, stream>>>(fr_logit, lse, cand, cost_g, transcript,
                                 labels, rowmap, fr_part, la);
    k_la<<<dim3(TT / 32, BB), 256, 0, stream>>>(feat, rowmap, la);
    k_glcterm<<<dim3(LL, BB), 256, 0, stream>>>(feat, la, labels, terms);
    k_combine<<<1, 256, 0, stream>>>(tok_logit, vid, fr_part, terms, out);
}

// Round 15
// 168.129 us; speedup vs baseline: 1.0095x; 1.0095x over previous
//
#include <hip/hip_runtime.h>
#include <math.h>

// Problem constants (from reference)
#define BB 4
#define TT 2048
#define CC 48
#define DD 512
#define LL 16
#define NTR 15
#define NCAND 45
#define WINLEN 19   // int(T/L*0.15)
#define CSW 15
#define CCHALF 7

static __device__ __forceinline__ float wave_reduce_sum(float v) {
    for (int off = 32; off; off >>= 1) v += __shfl_down(v, off);
    return v;
}

// DPP max step
#define DPPMAX(x, ctrl) fmaxf((x), __int_as_float(__builtin_amdgcn_update_dpp( \
    __float_as_int(x), __float_as_int(x), (ctrl), 0xF, 0xF, false)))

// ---------------- Kernel 1: row log-sum-exp only ----------------
__global__ __launch_bounds__(256) void k_lse(const float* __restrict__ fr,
                                             float* __restrict__ lse) {
    int row = blockIdx.x * 4 + (threadIdx.x >> 6);   // 4 rows/block
    int lane = threadIdx.x & 63;
    float xv = (lane < CC) ? fr[(size_t)row * CC + lane] : -INFINITY;
    float m = xv;
    for (int off = 32; off; off >>= 1) m = fmaxf(m, __shfl_down(m, off));
    m = __shfl(m, 0);
    float e = (lane < CC) ? __expf(xv - m) : 0.f;
    float s = wave_reduce_sum(e);
    if (lane == 0) lse[row] = m + __logf(s);
}

// ---------------- Kernel 2: boundary (JS) score, 4 t's/block (shared staging) ----------------
__global__ __launch_bounds__(256) void k_score(const float* __restrict__ fr,
                                               const float* __restrict__ lse,
                                               float* __restrict__ score) {
    int t_base = (blockIdx.x * 4) % TT;
    int b = (blockIdx.x * 4) / TT;
    __shared__ float sp[12][CC];
    __shared__ float slp[12][CC];
    __shared__ float lse_s[12];
    int tid = threadIdx.x;
    int wave = tid >> 6, lane = tid & 63;
    if (tid < 12) {
        int r = t_base - 4 + tid;
        lse_s[tid] = (r >= 0 && r < TT) ? lse[b * TT + r] : 0.f;
    }
    __syncthreads();
    for (int idx = tid; idx < 12 * CC; idx += 256) {
        int i = idx / CC, c = idx - (idx / CC) * CC;
        int r = t_base - 4 + i;
        float pv = 0.f, lv = 0.f;
        if (r >= 0 && r < TT) {
            float x = fr[((size_t)b * TT + r) * CC + c];
            lv = x - lse_s[i];
            pv = __expf(lv);
        }
        sp[i][c] = pv;
        slp[i][c] = lv;
    }
    __syncthreads();
    int t = t_base + wave;
    float acc = 0.f;
    for (int idx = lane; idx < 4 * CC; idx += 64) {
        int i = idx / CC, c = idx - (idx / CC) * CC;
        acc += -2.f * sp[wave + i][c] * slp[wave + i][c];
    }
    for (int item = lane; item < 36 * CC; item += 64) {
        int pidx = item / CC, c = item - pidx * CC;
        int i = 0, rem = pidx;
        while (rem >= 8 - i) { rem -= 8 - i; ++i; }
        int j = i + 1 + rem;
        float wgt = ((i < 4) == (j < 4)) ? 1.f : -1.f;
        float pi = sp[wave + i][c], pj = sp[wave + j][c];
        float logm = __logf(0.5f * (pi + pj) + 1e-32f);
        acc -= wgt * (pi + pj) * logm;
    }
    acc = wave_reduce_sum(acc);
    if (lane == 0) {
        const float SC = -2.0f / (81.0f * 0.6931471805599453f);
        score[(size_t)b * TT + t] = (t == 0) ? -INFINITY : SC * acc;
    }
}

// ---------------- Kernel 3: greedy pick, single wave, register-resident ----------------
__global__ __launch_bounds__(64) void k_pick(const float* __restrict__ score,
                                             int* __restrict__ cand,
                                             float* __restrict__ backup) {
    int b = blockIdx.x;
    int lane = threadIdx.x;
    __shared__ float s[64 * 33];
    __shared__ int cl[NCAND];
    for (int t = lane; t < TT; t += 64) s[t + (t >> 5)] = score[(size_t)b * TT + t];
    __syncthreads();
    float v[32];
    #pragma unroll
    for (int k = 0; k < 32; ++k) v[k] = s[lane * 33 + k];   // stride-33: conflict-free
    int base = lane << 5;
    for (int it = 0; it < NCAND; ++it) {
        float best = -INFINITY; int bi = 0;
        #pragma unroll
        for (int k = 31; k >= 0; --k)
            if (v[k] >= best) { best = v[k]; bi = k; }
        float m = best;
        m = DPPMAX(m, 0x111); m = DPPMAX(m, 0x112);
        m = DPPMAX(m, 0x114); m = DPPMAX(m, 0x118);
        m = DPPMAX(m, 0x142); m = DPPMAX(m, 0x143);
        float gmax = __int_as_float(__builtin_amdgcn_readlane(__float_as_int(m), 63));
        unsigned long long ball = __ballot(best == gmax);
        int sl = (int)(__ffsll((long long)ball) - 1);
        int mp = __builtin_amdgcn_readlane(base + bi, sl);
        if (lane == 0) cl[it] = mp;
        int llo = mp - WINLEN - base;
        int lhi = mp + WINLEN - base;
        unsigned lowm = (llo <= 0) ? 0xffffffffu : ((llo >= 32) ? 0u : ~((1u << llo) - 1u));
        unsigned him  = (lhi >= 31) ? 0xffffffffu : ((lhi < 0) ? 0u : ((2u << lhi) - 1u));
        unsigned wm = lowm & him;
        #pragma unroll
        for (int k = 0; k < 32; ++k)
            if (wm & (1u << k)) v[k] = -INFINITY;
    }
    __syncthreads();
    if (lane < NCAND) {
        int my = cl[lane];
        int rank = 0;
        for (int i = 0; i < NCAND; ++i) rank += (cl[i] < my) ? 1 : 0;
        cand[b * 64 + rank] = my;
        backup[b * 64 + rank] = s[my + (my >> 5)];
    }
}

// ---------------- Kernel 4: cls cost, one block per (candidate, batch) ----------------
__global__ __launch_bounds__(256) void k_cls(const float* __restrict__ fr,
                                             const float* __restrict__ lse,
                                             const int* __restrict__ cand,
                                             const float* __restrict__ backup,
                                             const int* __restrict__ transcript,
                                             float* __restrict__ cost_g) {
    int ii = blockIdx.x, b = blockIdx.y;
    __shared__ float win[CSW][LL + 1];
    __shared__ int tr_s[LL];
    int tid = threadIdx.x;
    if (tid < LL) tr_s[tid] = transcript[b * LL + tid];
    __syncthreads();
    int cpos = cand[b * 64 + ii];
    if (tid < CSW * LL) {
        int k = tid >> 4, m2 = tid & 15;
        int r = cpos - CCHALF + k;
        float p = 0.f;
        if (r >= 0 && r < TT) {
            size_t ro = (size_t)b * TT + r;
            p = __expf(fr[ro * CC + tr_s[m2]] - lse[ro]);
        }
        win[k][m2] = p;
    }
    __syncthreads();
    if (tid < NTR) {
        int j = tid;
        float sum = 0.f;
        #pragma unroll
        for (int k = 0; k < CSW; ++k)
            sum += ((k < CCHALF) ? 1.f : -1.f) * (win[k][j] - win[k][j + 1]);
        cost_g[(b * NTR + j) * NCAND + ii] = -(sum / 30.f + backup[b * 64 + ii]);
    }
}

// ---------------- Kernel 5: DP + backtrack + rank + frCE + la-zero ----------------
__global__ __launch_bounds__(256) void k_dp(const float* __restrict__ fr,
                                            const float* __restrict__ lse,
                                            const int* __restrict__ cand,
                                            const float* __restrict__ cost_g,
                                            const int* __restrict__ transcript,
                                            int* __restrict__ labels_out,
                                            int* __restrict__ rowmap,
                                            float* __restrict__ fr_part,
                                            float* __restrict__ la) {
    int b = blockIdx.x;
    __shared__ float cost[NTR][NCAND];
    __shared__ int tr_s[LL];
    __shared__ int cand_s[NCAND];
    __shared__ signed char dir_mat[NCAND][32];
    __shared__ int bdy_s[NTR];
    __shared__ int rank_s[LL];
    __shared__ float redf[4];
    int tid = threadIdx.x;
    int wave = tid >> 6, lane = tid & 63;
    if (tid < LL) tr_s[tid] = transcript[b * LL + tid];
    if (tid < NCAND) cand_s[tid] = cand[b * 64 + tid];

    // zero la for this batch (consumed later by k_la atomics)
    {
        float4 z = {0.f, 0.f, 0.f, 0.f};
        float4* lz = (float4*)(la + (size_t)b * LL * DD);
        #pragma unroll
        for (int i = 0; i < LL * DD / 4 / 256; ++i) lz[i * 256 + tid] = z;
    }
    // load precomputed cost matrix (675 floats)
    for (int e = tid; e < NTR * NCAND; e += 256) {
        int j = e / NCAND, ii = e - j * NCAND;
        cost[j][ii] = cost_g[b * NTR * NCAND + e];
    }
    __syncthreads();

    // ---- DP (wave 0, state j = lane j, W=31) ----
    if (tid < 64) {
        float prev = INFINITY;
        if (tid == 0) prev = 0.f;
        if (tid == 1) prev = cost[0][0];
        if (tid < 31) dir_mat[0][tid] = (tid == 1) ? (signed char)1 : (signed char)0;
        for (int ii = 1; ii < NCAND; ++ii) {
            float dm1 = __shfl_up(prev, 1); if (tid < 1) dm1 = INFINITY;
            float dm2 = __shfl_up(prev, 2); if (tid < 2) dm2 = INFINITY;
            int trat = tid >> 1; if (trat > NTR - 1) trat = NTR - 1;
            float c_at = cost[trat][ii];
            float ev = fminf(prev, dm1);
            int ed = (prev < dm1) ? 0 : 1;
            float ov = c_at + fminf(dm1, dm2);
            int od = (dm1 < dm2) ? 1 : 2;
            float nv; int nd;
            if (tid >= 2) {
                if ((tid & 1) == 0) { nv = ev; nd = ed; }
                else { nv = ov; nd = od; }
            } else { nv = INFINITY; nd = 0; }
            if (tid == 0) { nv = (ii < NCAND - NTR) ? 0.f : INFINITY; nd = 0; }
            if (tid == 1) {
                nv = (ii <= NCAND - NTR) ? cost[0][ii] : INFINITY;
                nd = (ii <= NCAND - NTR) ? 1 : 0;
            }
            prev = nv;
            if (tid < 31) dir_mat[ii][tid] = (signed char)nd;
        }
        float v29 = __shfl(prev, 29);
        float v30 = __shfl(prev, 30);
        if (tid == 0) {
            int cur = (v30 < v29) ? 30 : 29;
            for (int ii = NCAND - 1; ii >= 0; --ii) {
                if (cur & 1) bdy_s[cur >> 1] = cand_s[ii];
                cur -= (int)dir_mat[ii][cur];
            }
        }
    }
    __syncthreads();

    // ---- parallel rank (transcript values distinct) ----
    if (tid < LL) {
        int myv = tr_s[tid];
        int r2 = 0;
        #pragma unroll
        for (int l2 = 0; l2 < LL; ++l2) r2 += (tr_s[l2] < myv) ? 1 : 0;
        rank_s[tid] = r2;
        labels_out[b * LL + r2] = myv;   // sorted scatter
    }
    __syncthreads();

    // ---- fr CE partial + rowmap (pse inline) ----
    float facc = 0.f;
    for (int t = tid; t < TT; t += 256) {
        int cnt = 0;
        #pragma unroll
        for (int j = 0; j < NTR; ++j) cnt += (t >= bdy_s[j]) ? 1 : 0;
        int pv = tr_s[cnt];
        rowmap[b * TT + t] = rank_s[cnt];
        size_t ro = (size_t)b * TT + t;
        facc += lse[ro] - fr[ro * CC + pv];
    }
    facc = wave_reduce_sum(facc);
    if (lane == 0) redf[wave] = facc;
    __syncthreads();
    if (tid == 0) fr_part[b] = redf[0] + redf[1] + redf[2] + redf[3];
}

// ---------------- Kernel 6: segment feature sums, tile-scatter (atomics) ----------------
__global__ __launch_bounds__(256) void k_la(const float* __restrict__ feat,
                                            const int* __restrict__ rowmap,
                                            float* __restrict__ la) {
    int b = blockIdx.y;
    int t0 = blockIdx.x * 32;
    int tid = threadIdx.x;
    const float* frf = feat + ((size_t)b * (CC + TT) + CC) * DD;
    __shared__ int rm[32];
    if (tid < 32) rm[tid] = rowmap[b * TT + t0 + tid];
    __syncthreads();
    float ax = 0.f, ay = 0.f;
    int cur = rm[0];
    for (int k = 0; k < 32; ++k) {
        int r = rm[k];
        if (r != cur) {   // block-uniform branch
            float* dst = la + ((size_t)b * LL + cur) * DD + tid * 2;
            atomicAdd(dst, ax);
            atomicAdd(dst + 1, ay);
            ax = 0.f; ay = 0.f; cur = r;
        }
        const float2* p = (const float2*)(frf + (size_t)(t0 + k) * DD);
        float2 v = p[tid];
        ax += v.x; ay += v.y;
    }
    float* dst = la + ((size_t)b * LL + cur) * DD + tid * 2;
    atomicAdd(dst, ax);
    atomicAdd(dst + 1, ay);
}

// ---------------- Kernel 7: glc dots per (b,c): tok row staged, 16 dots + ntk ----------------
__global__ __launch_bounds__(256) void k_glc(const float* __restrict__ feat,
                                             const float* __restrict__ la,
                                             float* __restrict__ dots,
                                             float* __restrict__ ntk) {
    int c = blockIdx.x, b = blockIdx.y;
    __shared__ float tok_s[DD];
    __shared__ float redv[4];
    int tid = threadIdx.x;
    int wave = tid >> 6, lane = tid & 63;
    const float* tr = feat + ((size_t)b * (CC + TT) + c) * DD;
    float2 tv = ((const float2*)tr)[tid];
    ((float2*)tok_s)[tid] = tv;
    float vv = tv.x * tv.x + tv.y * tv.y;
    vv = wave_reduce_sum(vv);
    if (lane == 0) redv[wave] = vv;
    __syncthreads();
    if (tid == 0)
        ntk[b * CC + c] = fmaxf(sqrtf(redv[0] + redv[1] + redv[2] + redv[3]), 1e-12f);
    for (int l = wave; l < LL; l += 4) {
        const float4* lar = (const float4*)(la + ((size_t)b * LL + l) * DD);
        const float4* ts = (const float4*)tok_s;
        float dot = 0.f;
        #pragma unroll
        for (int jj = 0; jj < 2; ++jj) {
            int j = lane + jj * 64;
            float4 a = lar[j]; float4 w = ts[j];
            dot += a.x * w.x + a.y * w.y + a.z * w.z + a.w * w.w;
        }
        dot = wave_reduce_sum(dot);
        if (lane == 0) dots[((size_t)b * LL + l) * CC + c] = dot;
    }
}

// ---------------- Kernel 8: per-(b,l) term: nla + logsumexp ----------------
__global__ __launch_bounds__(64) void k_term(const float* __restrict__ la,
                                             const float* __restrict__ dots,
                                             const float* __restrict__ ntk,
                                             const int* __restrict__ labels,
                                             float* __restrict__ terms) {
    int l = blockIdx.x, b = blockIdx.y;
    int lane = threadIdx.x;
    const float4* lar = (const float4*)(la + ((size_t)b * LL + l) * DD);
    float ss = 0.f;
    #pragma unroll
    for (int jj = 0; jj < 2; ++jj) {
        float4 a = lar[lane + jj * 64];
        ss += a.x * a.x + a.y * a.y + a.z * a.z + a.w * a.w;
    }
    ss = wave_reduce_sum(ss);
    float nla = fmaxf(sqrtf(__shfl(ss, 0)), 1e-12f);
    float sim = -INFINITY;
    if (lane < CC)
        sim = dots[((size_t)b * LL + l) * CC + lane] * 10.0f / (nla * ntk[b * CC + lane]);
    float mx = sim;
    for (int off = 32; off; off >>= 1) mx = fmaxf(mx, __shfl_down(mx, off));
    mx = __shfl(mx, 0);
    float e = (lane < CC) ? expf(sim - mx) : 0.f;
    float se = wave_reduce_sum(e);
    se = __shfl(se, 0);
    int lab = labels[b * LL + l];
    float sim_lab = __shfl(sim, lab);
    if (lane == 0) terms[b * LL + l] = (mx + logf(se)) - sim_lab;
}

// ---------------- Kernel 9: combine ----------------
__global__ __launch_bounds__(256) void k_combine(const float* __restrict__ tok_logit,
                                                 const float* __restrict__ vid,
                                                 const float* __restrict__ fr_part,
                                                 const float* __restrict__ terms,
                                                 float* __restrict__ out) {
    int tid = threadIdx.x;
    __shared__ float red[4];
    __shared__ float gterm;
    float acc = 0.f;
    if (tid < BB * CC) {
        float x = tok_logit[tid], y = vid[tid];
        float lsp = fminf(x, 0.f) - log1pf(expf(-fabsf(x)));
        float lsn = fminf(-x, 0.f) - log1pf(expf(-fabsf(x)));
        acc = -(y * lsp + (1.f - y) * lsn);
    }
    float w = wave_reduce_sum(acc);
    if ((tid & 63) == 0) red[tid >> 6] = w;
    if (tid < 64) {
        float g = terms[tid];
        g = wave_reduce_sum(g);
        if (tid == 0) gterm = g;
    }
    __syncthreads();
    if (tid == 0) {
        float s_tok = (red[0] + red[1] + red[2] + red[3]) / (float)(BB * CC);
        float sfr = fr_part[0] + fr_part[1] + fr_part[2] + fr_part[3];
        float s_fr = sfr / (float)(BB * TT);
        float glc = gterm / (float)(BB * LL);
        out[0] = s_tok + s_fr + 0.1f * glc;
    }
}

extern "C" void kernel_launch(void* const* d_in, const int* in_sizes, int n_in,
                              void* d_out, int out_size, void* d_ws, size_t ws_size,
                              hipStream_t stream) {
    (void)in_sizes; (void)n_in; (void)out_size; (void)ws_size;
    // input order: epoch, tok_logit, fr_logit, mask, transcript, vid_multi_hot, feat
    const float* tok_logit  = (const float*)d_in[1];
    const float* fr_logit   = (const float*)d_in[2];
    const int*   transcript = (const int*)d_in[4];
    const float* vid        = (const float*)d_in[5];
    const float* feat       = (const float*)d_in[6];

    char* ws = (char*)d_ws;
    float* lse     = (float*)(ws + 0);        // B*T (32768 B)
    float* score   = (float*)(ws + 32768);    // B*T (32768 B)
    float* la      = (float*)(ws + 65536);    // B*L*D (131072 B)
    float* dots    = (float*)(ws + 196608);   // B*L*C (12288 B)
    float* ntk     = (float*)(ws + 208896);   // B*C
    float* terms   = (float*)(ws + 209664);   // B*L
    float* fr_part = (float*)(ws + 209920);   // 4
    int*   labels  = (int*)(ws + 210176);     // B*L
    int*   rowmap  = (int*)(ws + 210432);     // B*T (32768 B)
    int*   cand    = (int*)(ws + 243200);     // B*64
    float* backup  = (float*)(ws + 244224);   // B*64
    float* cost_g  = (float*)(ws + 245248);   // B*NTR*NCAND (10800 B)
    float* out     = (float*)d_out;

    k_lse<<<BB * TT / 4, 256, 0, stream>>>(fr_logit, lse);
    k_score<<<BB * TT / 4, 256, 0, stream>>>(fr_logit, lse, score);
    k_pick<<<BB, 64, 0, stream>>>(score, cand, backup);
    k_cls<<<dim3(NCAND, BB), 256, 0, stream>>>(fr_logit, lse, cand, backup,
                                               transcript, cost_g);
    k_dp<<<BB, 256, 0, stream>>>(fr_logit, lse, cand, cost_g, transcript,
                                 labels, rowmap, fr_part, la);
    k_la<<<dim3(TT / 32, BB), 256, 0, stream>>>(feat, rowmap, la);
    k_glc<<<dim3(CC, BB), 256, 0, stream>>>(feat, la, dots, ntk);
    k_term<<<dim3(LL, BB), 64, 0, stream>>>(la, dots, ntk, labels, terms);
    k_combine<<<1, 256, 0, stream>>>(tok_logit, vid, fr_part, terms, out);
}